// Round 1
// baseline (470.352 us; speedup 1.0000x reference)
//
#include <hip/hip_runtime.h>
#include <stdint.h>

#define IN    4096
#define OUT   4096
#define BATCH 8192
#define TK    64
#define BT    8     // batch rows per block in the spmm kernel

// ---------------------------------------------------------------------------
// Kernel 1: per output row, select top-64 entries of pre_w, emit compact
// sparse weights wt[k][o] = {idx, float_bits(exp(pre_w)*sign)}  (layout [TK][OUT])
// ---------------------------------------------------------------------------
__global__ __launch_bounds__(256)
void topk_build_kernel(const float* __restrict__ pre_w,
                       const float* __restrict__ sign_m,
                       int2* __restrict__ wt) {
  __shared__ uint32_t keys[IN];     // order-preserving uint transform of fp32
  __shared__ int red[4];
  __shared__ int bc;
  __shared__ int cnt_gt, cnt_tie;
  __shared__ int sel[TK];

  const int row = blockIdx.x;
  const int tid = threadIdx.x;
  const float* pw = pre_w + (size_t)row * IN;

  for (int i = tid; i < IN; i += 256) {
    uint32_t u = __float_as_uint(pw[i]);
    keys[i] = (u & 0x80000000u) ? ~u : (u | 0x80000000u);
  }
  if (tid == 0) { cnt_gt = 0; cnt_tie = 0; }
  __syncthreads();

  // binary search (MSB-greedy) for largest threshold T with count(key >= T) >= TK
  uint32_t cur = 0u;
  for (int b = 31; b >= 0; --b) {
    const uint32_t cand = cur | (1u << b);
    int c = 0;
    for (int i = tid; i < IN; i += 256) c += (keys[i] >= cand) ? 1 : 0;
    #pragma unroll
    for (int off = 32; off > 0; off >>= 1) c += __shfl_down(c, off, 64);
    if ((tid & 63) == 0) red[tid >> 6] = c;
    __syncthreads();
    if (tid == 0) {
      const int tot = red[0] + red[1] + red[2] + red[3];
      bc = (tot >= TK) ? 1 : 0;
    }
    __syncthreads();
    if (bc) cur = cand;
  }

  // select: all keys > T, then fill with == T up to TK (tie handling)
  for (int i = tid; i < IN; i += 256) {
    if (keys[i] > cur) {
      const int p = atomicAdd(&cnt_gt, 1);
      sel[p] = i;   // count(> T) < TK guaranteed
    }
  }
  __syncthreads();
  const int ng = cnt_gt;
  for (int i = tid; i < IN; i += 256) {
    if (keys[i] == cur) {
      const int p = atomicAdd(&cnt_tie, 1);
      if (ng + p < TK) sel[ng + p] = i;
    }
  }
  __syncthreads();

  if (tid < TK) {
    const int idx = sel[tid];
    const float v = expf(pw[idx]) * sign_m[(size_t)row * IN + idx];
    wt[(size_t)tid * OUT + row] = make_int2(idx, __float_as_int(v));
  }
}

// ---------------------------------------------------------------------------
// Kernel 2: sparse matmul. Block = BT batch rows x all OUT outputs.
// x tile staged in LDS, bf16, transposed: LDS row i = 8 batch values = 16 B.
// One ds_read_b128 per (o,k) gather feeds 8 fp32 FMAs.
// ---------------------------------------------------------------------------
__device__ __forceinline__ uint32_t pack_bf16x2(float a, float b) {
  uint32_t ua = __float_as_uint(a);
  uint32_t ub = __float_as_uint(b);
  ua = (ua + 0x7FFFu + ((ua >> 16) & 1u)) >> 16;          // bf16(a) in low half
  ub = (ub + 0x7FFFu + ((ub >> 16) & 1u)) & 0xFFFF0000u;  // bf16(b) in high half
  return ua | ub;
}

__global__ __launch_bounds__(1024, 4)
void spmm_topk_kernel(const float* __restrict__ x,
                      const int2* __restrict__ wt,
                      float* __restrict__ out) {
  __shared__ uint16_t ldsx[IN * BT];   // 64 KB: row i at byte offset i*16

  const int tid = threadIdx.x;
  const int b0 = blockIdx.x * BT;

  // ---- stage: 8 rows of x -> LDS bf16 transposed ----
  {
    const int i4 = tid * 4;            // this thread owns features i4..i4+3
    float c[4][BT];
    #pragma unroll
    for (int j = 0; j < BT; ++j) {
      const float4 v = *(const float4*)(x + (size_t)(b0 + j) * IN + i4);
      c[0][j] = v.x; c[1][j] = v.y; c[2][j] = v.z; c[3][j] = v.w;
    }
    #pragma unroll
    for (int r = 0; r < 4; ++r) {
      uint4 pk;
      pk.x = pack_bf16x2(c[r][0], c[r][1]);
      pk.y = pack_bf16x2(c[r][2], c[r][3]);
      pk.z = pack_bf16x2(c[r][4], c[r][5]);
      pk.w = pack_bf16x2(c[r][6], c[r][7]);
      *(uint4*)(&ldsx[(i4 + r) * BT]) = pk;
    }
  }
  __syncthreads();

  // ---- compute: each lane owns one output column per group ----
  const int wave = tid >> 6;
  const int lane = tid & 63;

  for (int g = wave; g < (OUT / 64); g += 16) {   // 4 groups per wave
    const int o = g * 64 + lane;
    float a0 = 0.f, a1 = 0.f, a2 = 0.f, a3 = 0.f;
    float a4 = 0.f, a5 = 0.f, a6 = 0.f, a7 = 0.f;
    const int2* wp = wt + o;

    #pragma unroll 4
    for (int k = 0; k < TK; ++k) {
      const int2 p = wp[(size_t)k * OUT];                       // coalesced dwordx2, L2-hot
      const uint4 xv = *(const uint4*)(&ldsx[p.x * BT]);        // ds_read_b128 gather
      const float val = __int_as_float(p.y);
      a0 = fmaf(__uint_as_float(xv.x << 16),        val, a0);
      a1 = fmaf(__uint_as_float(xv.x & 0xFFFF0000u), val, a1);
      a2 = fmaf(__uint_as_float(xv.y << 16),        val, a2);
      a3 = fmaf(__uint_as_float(xv.y & 0xFFFF0000u), val, a3);
      a4 = fmaf(__uint_as_float(xv.z << 16),        val, a4);
      a5 = fmaf(__uint_as_float(xv.z & 0xFFFF0000u), val, a5);
      a6 = fmaf(__uint_as_float(xv.w << 16),        val, a6);
      a7 = fmaf(__uint_as_float(xv.w & 0xFFFF0000u), val, a7);
    }

    float* op = out + (size_t)b0 * OUT + o;
    op[0 * OUT] = a0; op[1 * OUT] = a1; op[2 * OUT] = a2; op[3 * OUT] = a3;
    op[4 * OUT] = a4; op[5 * OUT] = a5; op[6 * OUT] = a6; op[7 * OUT] = a7;
  }
}

// ---------------------------------------------------------------------------
extern "C" void kernel_launch(void* const* d_in, const int* in_sizes, int n_in,
                              void* d_out, int out_size, void* d_ws, size_t ws_size,
                              hipStream_t stream) {
  const float* x      = (const float*)d_in[0];
  const float* pre_w  = (const float*)d_in[1];
  const float* sign_m = (const float*)d_in[2];
  float* out = (float*)d_out;
  int2* wt = (int2*)d_ws;   // [TK][OUT] = 2 MB scratch

  topk_build_kernel<<<OUT, 256, 0, stream>>>(pre_w, sign_m, wt);
  spmm_topk_kernel<<<BATCH / BT, 1024, 0, stream>>>(x, wt, out);
}